// Round 12
// baseline (130.933 us; speedup 1.0000x reference)
//
#include <hip/hip_runtime.h>
#include <hip/hip_bf16.h>
#include <stdint.h>

#define BATCH 2
#define SEQ   2048
#define DIM   1024
#define NH    16
#define HD    64
#define MVAL  (-10000.0f)

// Native exp2 (raw v_exp_f32, no libm fixup). Fallback: e-domain with __expf.
#if __has_builtin(__builtin_amdgcn_exp2f)
#define EXP2(x) __builtin_amdgcn_exp2f(x)
#define QSCALE  (0.125f * 1.44269504f)   // fold softmax scale AND log2(e) into Q
#else
#define EXP2(x) __expf(x)
#define QSCALE  0.125f
#endif

typedef __attribute__((ext_vector_type(8))) short bf16x8;
typedef __attribute__((ext_vector_type(4))) float f32x4;
typedef __attribute__((ext_vector_type(16))) float f32x16;
typedef unsigned short u16;

static __device__ __forceinline__ u16 f2bf(float f) {
  union { float f; uint32_t u; } c; c.f = f;
  uint32_t x = c.u;
  return (u16)((x + 0x7fffu + ((x >> 16) & 1u)) >> 16);  // RNE
}

static __device__ __forceinline__ uint32_t pk2(float a, float b) {
  __hip_bfloat162 h = __float22bfloat162_rn(make_float2(a, b));
  union { __hip_bfloat162 h; uint32_t u; } c; c.h = h;
  return c.u;
}

// swizzled byte offset within LDS tiles of 128B rows (8 x 16B chunks)
static __device__ __forceinline__ int swz128(int row, int chunk) {
  return row * 128 + (((chunk ^ (row & 7)) & 7) << 4);
}

static __device__ __forceinline__ void gload_lds16(const void* g, void* l) {
  __builtin_amdgcn_global_load_lds((const __attribute__((address_space(1))) void*)g,
                                   (__attribute__((address_space(3))) void*)l, 16, 0, 0);
}

// -------- fused prep: fp32->bf16 convert of x + both weight transposes --------
__global__ void prep_kernel(const float* __restrict__ x, u16* __restrict__ xb,
                            const float* __restrict__ Wqkv, u16* __restrict__ WqkvT,
                            const float* __restrict__ Wout, u16* __restrict__ WoutT) {
  __shared__ float tile[32][33];
  int blk = blockIdx.x, tid = threadIdx.x;
  if (blk < 4096) {
    int i = blk * 256 + tid;
    float4 v = reinterpret_cast<const float4*>(x)[i];
    reinterpret_cast<uint2*>(xb)[i] = make_uint2(pk2(v.x, v.y), pk2(v.z, v.w));
    return;
  }
  const float* in;
  u16* out;
  int C, t;
  if (blk < 4096 + 3072) { t = blk - 4096; in = Wqkv; out = WqkvT; C = 3072; }
  else                   { t = blk - 7168; in = Wout; out = WoutT; C = 1024; }
  int R = DIM;
  int c0 = (t % (C / 32)) * 32, r0 = (t / (C / 32)) * 32;
  int tx = tid & 31, ty = tid >> 5;
#pragma unroll
  for (int i = 0; i < 32; i += 8)
    tile[ty + i][tx] = in[(size_t)(r0 + ty + i) * C + c0 + tx];
  __syncthreads();
#pragma unroll
  for (int i = 0; i < 32; i += 8)
    out[(size_t)(c0 + ty + i) * R + r0 + tx] = f2bf(tile[tx][ty + i]);
}

// ------- bf16 [bh][s][64] -> [bh][64][s] transpose (V for attention) -------
__global__ void vtrans_kernel(const u16* __restrict__ Vi, u16* __restrict__ Vo) {
  __shared__ __align__(16) char t[8192];  // 64 x 64 u16, XOR-swizzled rows
  int tid = threadIdx.x;
  int bh = blockIdx.y, s0 = blockIdx.x * 64;
  const u16* src = Vi + ((size_t)bh * SEQ + s0) * HD;
#pragma unroll
  for (int i = 0; i < 2; i++) {
    int r = i * 32 + (tid >> 3), ch = tid & 7;
    uint4 v = *reinterpret_cast<const uint4*>(src + (size_t)r * HD + ch * 8);
    *reinterpret_cast<uint4*>(t + swz128(r, ch)) = v;
  }
  __syncthreads();
  int d = tid >> 2, sc = tid & 3;  // d-row; 16 consecutive s starting at sc*16
  u16 vals[16];
#pragma unroll
  for (int j = 0; j < 16; j++) {
    int s = sc * 16 + j;
    vals[j] = *reinterpret_cast<const u16*>(
        t + s * 128 + ((((d >> 3) ^ (s & 7)) & 7) << 4) + (d & 7) * 2);
  }
  u16* dst = Vo + ((size_t)bh * HD + d) * SEQ + s0 + sc * 16;
  *reinterpret_cast<uint4*>(dst) = *reinterpret_cast<const uint4*>(vals);
  *reinterpret_cast<uint4*>(dst + 8) = *reinterpret_cast<const uint4*>(vals + 8);
}

// ---------------- bf16 GEMM: C = A[M,K] * Bt[N,K]^T + bias ----------------
template <int EPI>
__global__ __launch_bounds__(256, 2) void gemm_bt_kernel(
    const u16* __restrict__ A, const u16* __restrict__ Bt,
    const float* __restrict__ bias, float* __restrict__ Cout,
    u16* __restrict__ Qo, u16* __restrict__ Ko, u16* __restrict__ Vo,
    int M, int N, int K) {
  __shared__ __align__(16) char lds[32768];
  char* As = lds;            // 128 rows x 64 bf16, swizzled
  char* Bs = lds + 16384;
  int tid = threadIdx.x;
  int lane = tid & 63, l15 = lane & 15, l4 = lane >> 4;
  int w = tid >> 6, wr = w >> 1, wc = w & 1;
  int m0 = blockIdx.y * 128, n0 = blockIdx.x * 128;
  int srow = tid >> 3, sch = tid & 7;
  int sc_swz = ((sch ^ (srow & 7)) << 3);  // pre-swizzled source chunk (u16 units)

  const u16* Ap = A + (size_t)(m0 + srow) * K + sc_swz;
  const u16* Bp = Bt + (size_t)(n0 + srow) * K + sc_swz;

  f32x4 acc[4][4] = {};  // acc[nj][mi]: quad holds 4 consecutive n

  for (int k0 = 0; k0 < K; k0 += 64) {
    __syncthreads();
#pragma unroll
    for (int i = 0; i < 4; i++) {
      gload_lds16(Ap + (size_t)i * 32 * K + k0, As + i * 4096 + tid * 16);
      gload_lds16(Bp + (size_t)i * 32 * K + k0, Bs + i * 4096 + tid * 16);
    }
    __syncthreads();
#pragma unroll
    for (int ks = 0; ks < 2; ks++) {
      int ch = ks * 4 + l4;
      bf16x8 af[4], bfv[4];
#pragma unroll
      for (int mi = 0; mi < 4; mi++)
        af[mi] = *reinterpret_cast<const bf16x8*>(As + swz128(wr * 64 + mi * 16 + l15, ch));
#pragma unroll
      for (int nj = 0; nj < 4; nj++)
        bfv[nj] = *reinterpret_cast<const bf16x8*>(Bs + swz128(wc * 64 + nj * 16 + l15, ch));
#pragma unroll
      for (int nj = 0; nj < 4; nj++)
#pragma unroll
        for (int mi = 0; mi < 4; mi++)
          acc[nj][mi] = __builtin_amdgcn_mfma_f32_16x16x32_bf16(bfv[nj], af[mi], acc[nj][mi], 0, 0, 0);
    }
  }

  // epilogue: lane holds C[m][nb..nb+3], m = ..+l15, nb = ..+l4*4
#pragma unroll
  for (int nj = 0; nj < 4; nj++) {
    int nb = n0 + wc * 64 + nj * 16 + l4 * 4;
    float4 bv = *reinterpret_cast<const float4*>(bias + nb);
#pragma unroll
    for (int mi = 0; mi < 4; mi++) {
      int m = m0 + wr * 64 + mi * 16 + l15;
      f32x4 a = acc[nj][mi];
      float v0 = a[0] + bv.x, v1 = a[1] + bv.y, v2 = a[2] + bv.z, v3 = a[3] + bv.w;
      if (EPI == 1) {
        *reinterpret_cast<float4*>(Cout + (size_t)m * N + nb) = make_float4(v0, v1, v2, v3);
      } else {
        int b = m >> 11, s = m & 2047;
        int sec = nb >> 10, c = nb & 1023, h = c >> 6, d = c & 63;  // sec,h wave-uniform
        size_t bh = (size_t)(b * NH + h);
        u16* dst;
        float scl;
        if (sec == 0)      { dst = Qo; scl = QSCALE; }
        else if (sec == 1) { dst = Ko; scl = 1.0f; }
        else               { dst = Vo; scl = 1.0f; }
        *reinterpret_cast<uint2*>(dst + (bh * SEQ + s) * HD + d) =
            make_uint2(pk2(v0 * scl, v1 * scl), pk2(v2 * scl, v3 * scl));
      }
    }
  }
}

// ------- causal flash attention: wave-private pipelines, barrier-free loop -------
// 1024 blocks x 256 thr. Block = job (bh, pair p): chunks (63-p) then (p), 32 q-rows.
// Wave w owns kv tiles T == w (mod 4), 64-wide, with PRIVATE K double-buffer
// (16KB/wave; vmcnt is wave-local -> no __syncthreads in the main loop). V direct
// global->reg issued one step early, consumed by deferred PV. 32x32 swapped MFMA,
// in-register P (cvt_pk + permlane32_swap). 4-way merge via dead K buffers,
// 2 barriers per pass only.
__global__ __launch_bounds__(256, 2) void attn_kernel(
    const u16* __restrict__ Q, const u16* __restrict__ K,
    const u16* __restrict__ Vt, u16* __restrict__ O) {
  __shared__ __align__(16) char lds[65536];  // 4 waves x (2 x 8KB K dbuf)
  int tid = threadIdx.x, lane = tid & 63, w = tid >> 6;
  int l31 = lane & 31, hi = lane >> 5;
  int par = w;
  int blk = blockIdx.x;
  int bh = (blk & 7) * 4 + ((blk >> 3) & 3);   // XCD-clustered: 4 bh per XCD
  int p = blk >> 5;                            // [0,32)
  const u16* Qh = Q + (size_t)bh * SEQ * HD;
  const u16* Kh = K + (size_t)bh * SEQ * HD;
  const u16* Vh = Vt + (size_t)bh * HD * SEQ;
  char* myK = lds + w * 16384;
  int b_ = bh >> 4, h_ = bh & 15;
  int sr = lane >> 3, sc = lane & 7;

  // stage one 64-wide K tile into my private buffer half (linear dest, swz src)
  auto stageK = [&](int b, int T) {
    const u16* Kt = Kh + (size_t)T * 64 * HD;
    char* Kb = myK + b * 8192;
#pragma unroll
    for (int i = 0; i < 8; i++) {
      int row = i * 8 + sr;
      int cch = (sc ^ sr) << 3;   // row&7 == sr
      gload_lds16(Kt + (size_t)row * HD + cch, Kb + i * 1024 + lane * 16);
    }
  };

  for (int pass = 0; pass < 2; pass++) {
    int c = pass ? p : (63 - p);      // 32-row q-chunk index
    int nkt = (c + 2) >> 1;           // 64-wide kv tiles covering [0, 32c+32)
    int qb = c * 32;

    // Q^T B-operand fragments: lane holds Q[q=l31][ks*16 + hi*8 + j]
    bf16x8 qf[4];
#pragma unroll
    for (int ks = 0; ks < 4; ks++)
      qf[ks] = *reinterpret_cast<const bf16x8*>(
          Qh + (size_t)(qb + l31) * HD + ks * 16 + hi * 8);

    float mrun = -1e30f, lrun = 0.0f;
    f32x16 oacc[2] = {};
    bf16x8 pf_c[4], vf_c[2][4];
    bool pend = false;
    int buf = 0;

    if (par < nkt) stageK(0, par);

    for (int T = par; T < nkt; T += 4) {
      asm volatile("s_waitcnt vmcnt(0)" ::: "memory");
      __builtin_amdgcn_sched_barrier(0);
      if (T + 4 < nkt) stageK(buf ^ 1, T + 4);

      __builtin_amdgcn_s_setprio(1);
      // deferred PV(prev tile): pure-reg MFMAs overlap staging/ds_reads
      if (pend) {
#pragma unroll
        for (int ks = 0; ks < 4; ks++)
#pragma unroll
          for (int nd = 0; nd < 2; nd++)
            oacc[nd] = __builtin_amdgcn_mfma_f32_32x32x16_bf16(
                vf_c[nd][ks], pf_c[ks], oacc[nd], 0, 0, 0);
      }

      // S^T = K . Q^T from my private LDS
      char* Kw = myK + buf * 8192;
      f32x16 s[2] = {};
#pragma unroll
      for (int ks = 0; ks < 4; ks++)
#pragma unroll
        for (int n = 0; n < 2; n++) {
          bf16x8 kf = *reinterpret_cast<const bf16x8*>(
              Kw + swz128(n * 32 + l31, 2 * ks + hi));
          s[n] = __builtin_amdgcn_mfma_f32_32x32x16_bf16(kf, qf[ks], s[n], 0, 0, 0);
        }
      __builtin_amdgcn_s_setprio(0);

      // V fragments for THIS tile, direct global->reg (consumed next step)
      int kvb = T * 64;
      const u16* Vs = Vh + kvb;
#pragma unroll
      for (int nd = 0; nd < 2; nd++)
#pragma unroll
        for (int ks = 0; ks < 4; ks++)
          vf_c[nd][ks] = *reinterpret_cast<const bf16x8*>(
              Vs + (size_t)(nd * 32 + l31) * SEQ + (2 * ks + hi) * 8);

      // causal mask: only the diagonal tile
      if (kvb + 63 > qb) {
        int qg = qb + l31;
#pragma unroll
        for (int n = 0; n < 2; n++)
#pragma unroll
          for (int r = 0; r < 16; r++) {
            int kg = kvb + n * 32 + (r & 3) + 8 * (r >> 2) + 4 * hi;
            if (kg > qg) s[n][r] = MVAL;
          }
      }

      // row-max: in-lane over 32 + 1 cross-hi shuffle
      float mt = s[0][0];
#pragma unroll
      for (int n = 0; n < 2; n++)
#pragma unroll
        for (int r = 0; r < 16; r++) mt = fmaxf(mt, s[n][r]);
      mt = fmaxf(mt, __shfl_xor(mt, 32));

      // defer-max: skip rescale when running max unchanged (exact, THR=0)
      if (!__all(mt <= mrun)) {
        float mnew = fmaxf(mrun, mt);
        float alpha = EXP2(mrun - mnew);
        mrun = mnew;
#pragma unroll
        for (int nd = 0; nd < 2; nd++)
#pragma unroll
          for (int r = 0; r < 16; r++) oacc[nd][r] *= alpha;
        lrun *= alpha;
      }

      // P = exp2(s - m); in-lane sum + 1 shuffle
      float rs = 0.0f;
#pragma unroll
      for (int n = 0; n < 2; n++)
#pragma unroll
        for (int r = 0; r < 16; r++) {
          float pv = EXP2(s[n][r] - mrun);
          s[n][r] = pv;
          rs += pv;
        }
      rs += __shfl_xor(rs, 32);
      lrun += rs;

      // pack P into PV B-operand words: cvt_pk pairs + permlane32_swap
#pragma unroll
      for (int n = 0; n < 2; n++)
#pragma unroll
        for (int half = 0; half < 2; half++) {
          int rb = half * 8;
          uint32_t a0 = pk2(s[n][rb + 0], s[n][rb + 1]);
          uint32_t b0 = pk2(s[n][rb + 4], s[n][rb + 5]);
          asm("v_permlane32_swap_b32 %0, %1" : "+v"(a0), "+v"(b0));
          uint32_t a1 = pk2(s[n][rb + 2], s[n][rb + 3]);
          uint32_t b1 = pk2(s[n][rb + 6], s[n][rb + 7]);
          asm("v_permlane32_swap_b32 %0, %1" : "+v"(a1), "+v"(b1));
          union { uint32_t u[4]; bf16x8 v; } bw;
          bw.u[0] = a0; bw.u[1] = a1; bw.u[2] = b0; bw.u[3] = b1;
          pf_c[n * 2 + half] = bw.v;
        }
      pend = true;
      buf ^= 1;
    }

    // flush last pending PV
    if (pend) {
      __builtin_amdgcn_s_setprio(1);
#pragma unroll
      for (int ks = 0; ks < 4; ks++)
#pragma unroll
        for (int nd = 0; nd < 2; nd++)
          oacc[nd] = __builtin_amdgcn_mfma_f32_32x32x16_bf16(
              vf_c[nd][ks], pf_c[ks], oacc[nd], 0, 0, 0);
      __builtin_amdgcn_s_setprio(0);
    }

    // ---- 4-way merge through (dead) private K buffers ----
    int row = l31;
    if (par != 0) {
      if (hi == 0) {
        float* ml = (float*)(myK + 8192);
        ml[row * 2] = mrun;
        ml[row * 2 + 1] = lrun;
      }
#pragma unroll
      for (int nd = 0; nd < 2; nd++)
#pragma unroll
        for (int g = 0; g < 4; g++) {
          int chunk = 8 * nd + 2 * g + hi;
          f32x4 t;
          t[0] = oacc[nd][4 * g];     t[1] = oacc[nd][4 * g + 1];
          t[2] = oacc[nd][4 * g + 2]; t[3] = oacc[nd][4 * g + 3];
          *reinterpret_cast<f32x4*>(myK + row * 256 + (((chunk ^ (row & 7)) & 15) << 4)) = t;
        }
    }
    __syncthreads();
    if (par == 0) {
      float mK[3], lK[3];
      float mAll = mrun;
#pragma unroll
      for (int k = 0; k < 3; k++) {
        float* ml = (float*)(lds + (k + 1) * 16384 + 8192);
        mK[k] = ml[row * 2];
        lK[k] = ml[row * 2 + 1];
        mAll = fmaxf(mAll, mK[k]);
      }
      float wS = EXP2(mrun - mAll);
      float lT = lrun * wS;
      float wK[3];
#pragma unroll
      for (int k = 0; k < 3; k++) { wK[k] = EXP2(mK[k] - mAll); lT += lK[k] * wK[k]; }
      float linv = 1.0f / lT;
      u16* orow = O + ((size_t)b_ * SEQ + qb + l31) * DIM + h_ * HD;
#pragma unroll
      for (int nd = 0; nd < 2; nd++)
#pragma unroll
        for (int g = 0; g < 4; g++) {
          int chunk = 8 * nd + 2 * g + hi;
          int off = row * 256 + (((chunk ^ (row & 7)) & 15) << 4);
          float o0 = oacc[nd][4 * g] * wS;
          float o1 = oacc[nd][4 * g + 1] * wS;
          float o2 = oacc[nd][4 * g + 2] * wS;
          float o3 = oacc[nd][4 * g + 3] * wS;
#pragma unroll
          for (int k = 0; k < 3; k++) {
            f32x4 ob = *reinterpret_cast<const f32x4*>(lds + (k + 1) * 16384 + off);
            o0 += ob[0] * wK[k]; o1 += ob[1] * wK[k];
            o2 += ob[2] * wK[k]; o3 += ob[3] * wK[k];
          }
          int d0 = nd * 32 + 8 * g + 4 * hi;
          *reinterpret_cast<uint2*>(orow + d0) =
              make_uint2(pk2(o0 * linv, o1 * linv), pk2(o2 * linv, o3 * linv));
        }
    }
    __syncthreads();  // protect scratch before next pass's staging overwrites
  }
}

extern "C" void kernel_launch(void* const* d_in, const int* in_sizes, int n_in,
                              void* d_out, int out_size, void* d_ws, size_t ws_size,
                              hipStream_t stream) {
  const float* x     = (const float*)d_in[0];
  const float* W_qkv = (const float*)d_in[1];
  const float* b_qkv = (const float*)d_in[2];
  const float* W_out = (const float*)d_in[3];
  const float* b_out = (const float*)d_in[4];
  float* out = (float*)d_out;
  char* ws = (char*)d_ws;

  // ws layout (bytes)
  u16* xb    = (u16*)(ws);                               // 8 MB  [4096][1024]
  u16* WqkvT = (u16*)(ws + 8388608);                     // 6 MB  [3072][1024]
  u16* WoutT = (u16*)(ws + 8388608 + 6291456);           // 2 MB  [1024][1024]
  u16* Qb    = (u16*)(ws + 16777216);                    // 8 MB  [32][2048][64]
  u16* Kb    = (u16*)(ws + 16777216 + 8388608);          // 8 MB  [32][2048][64]
  u16* Vtb   = (u16*)(ws + 16777216 + 2 * 8388608);      // 8 MB  [32][64][2048]
  u16* Ob    = (u16*)(ws + 16777216 + 3 * 8388608);      // 8 MB  [4096][1024]
  u16* Vraw  = Ob;  // aliased: Vraw lifetime (gemm0->vtrans) disjoint from Ob (attn->gemm1)

  prep_kernel<<<4096 + 3072 + 1024, 256, 0, stream>>>(x, xb, W_qkv, WqkvT, W_out, WoutT);
  gemm_bt_kernel<0><<<dim3(3 * DIM / 128, BATCH * SEQ / 128), 256, 0, stream>>>(
      xb, WqkvT, b_qkv, nullptr, Qb, Kb, Vraw, BATCH * SEQ, 3 * DIM, DIM);
  vtrans_kernel<<<dim3(SEQ / 64, BATCH * NH), 256, 0, stream>>>(Vraw, Vtb);
  attn_kernel<<<1024, 256, 0, stream>>>(Qb, Kb, Vtb, Ob);
  gemm_bt_kernel<1><<<dim3(DIM / 128, BATCH * SEQ / 128), 256, 0, stream>>>(
      Ob, WoutT, b_out, out, nullptr, nullptr, nullptr, BATCH * SEQ, DIM, DIM);
}

// Round 13
// 111.970 us; speedup vs baseline: 1.1694x; 1.1694x over previous
//
#include <hip/hip_runtime.h>
#include <hip/hip_bf16.h>
#include <stdint.h>

#define BATCH 2
#define SEQ   2048
#define DIM   1024
#define NH    16
#define HD    64
#define MVAL  (-10000.0f)

// Native exp2 (raw v_exp_f32, no libm fixup). Fallback: e-domain with __expf.
#if __has_builtin(__builtin_amdgcn_exp2f)
#define EXP2(x) __builtin_amdgcn_exp2f(x)
#define QSCALE  (0.125f * 1.44269504f)   // fold softmax scale AND log2(e) into Q
#else
#define EXP2(x) __expf(x)
#define QSCALE  0.125f
#endif

typedef __attribute__((ext_vector_type(8))) short bf16x8;
typedef __attribute__((ext_vector_type(4))) float f32x4;
typedef unsigned short u16;

static __device__ __forceinline__ u16 f2bf(float f) {
  union { float f; uint32_t u; } c; c.f = f;
  uint32_t x = c.u;
  return (u16)((x + 0x7fffu + ((x >> 16) & 1u)) >> 16);  // RNE
}

static __device__ __forceinline__ uint32_t pk2(float a, float b) {
  __hip_bfloat162 h = __float22bfloat162_rn(make_float2(a, b));
  union { __hip_bfloat162 h; uint32_t u; } c; c.h = h;
  return c.u;
}

// swizzled byte offset within LDS tiles of 128B rows (8 x 16B chunks)
static __device__ __forceinline__ int swz128(int row, int chunk) {
  return row * 128 + (((chunk ^ (row & 7)) & 7) << 4);
}

static __device__ __forceinline__ void gload_lds16(const void* g, void* l) {
  __builtin_amdgcn_global_load_lds((const __attribute__((address_space(1))) void*)g,
                                   (__attribute__((address_space(3))) void*)l, 16, 0, 0);
}

// -------- fused prep: fp32->bf16 convert of x + both weight transposes --------
__global__ void prep_kernel(const float* __restrict__ x, u16* __restrict__ xb,
                            const float* __restrict__ Wqkv, u16* __restrict__ WqkvT,
                            const float* __restrict__ Wout, u16* __restrict__ WoutT) {
  __shared__ float tile[32][33];
  int blk = blockIdx.x, tid = threadIdx.x;
  if (blk < 4096) {
    int i = blk * 256 + tid;
    float4 v = reinterpret_cast<const float4*>(x)[i];
    reinterpret_cast<uint2*>(xb)[i] = make_uint2(pk2(v.x, v.y), pk2(v.z, v.w));
    return;
  }
  const float* in;
  u16* out;
  int C, t;
  if (blk < 4096 + 3072) { t = blk - 4096; in = Wqkv; out = WqkvT; C = 3072; }
  else                   { t = blk - 7168; in = Wout; out = WoutT; C = 1024; }
  int R = DIM;
  int c0 = (t % (C / 32)) * 32, r0 = (t / (C / 32)) * 32;
  int tx = tid & 31, ty = tid >> 5;
#pragma unroll
  for (int i = 0; i < 32; i += 8)
    tile[ty + i][tx] = in[(size_t)(r0 + ty + i) * C + c0 + tx];
  __syncthreads();
#pragma unroll
  for (int i = 0; i < 32; i += 8)
    out[(size_t)(c0 + ty + i) * R + r0 + tx] = f2bf(tile[tx][ty + i]);
}

// ---------------- bf16 GEMM: C = A[M,K] * Bt[N,K]^T + bias ----------------
// Swizzled LDS (pre-swizzled gload_lds source + swizzled ds_read_b128).
// SWAPPED mfma operands: lane's acc quad holds 4 consecutive n -> packed stores.
// EPI==0: Q (x QSCALE) / K head-split [bh][s][d] bf16 (8B stores);
//         V written TRANSPOSED [bh][d][s] directly (2B stores, 32B lane-runs).
// EPI==1: plain fp32 [M][N], 16B stores
template <int EPI>
__global__ __launch_bounds__(256, 2) void gemm_bt_kernel(
    const u16* __restrict__ A, const u16* __restrict__ Bt,
    const float* __restrict__ bias, float* __restrict__ Cout,
    u16* __restrict__ Qo, u16* __restrict__ Ko, u16* __restrict__ Vto,
    int M, int N, int K) {
  __shared__ __align__(16) char lds[32768];
  char* As = lds;            // 128 rows x 64 bf16, swizzled
  char* Bs = lds + 16384;
  int tid = threadIdx.x;
  int lane = tid & 63, l15 = lane & 15, l4 = lane >> 4;
  int w = tid >> 6, wr = w >> 1, wc = w & 1;
  int m0 = blockIdx.y * 128, n0 = blockIdx.x * 128;
  int srow = tid >> 3, sch = tid & 7;
  int sc_swz = ((sch ^ (srow & 7)) << 3);  // pre-swizzled source chunk (u16 units)

  const u16* Ap = A + (size_t)(m0 + srow) * K + sc_swz;
  const u16* Bp = Bt + (size_t)(n0 + srow) * K + sc_swz;

  f32x4 acc[4][4] = {};  // acc[nj][mi]: quad holds 4 consecutive n

  for (int k0 = 0; k0 < K; k0 += 64) {
    __syncthreads();
#pragma unroll
    for (int i = 0; i < 4; i++) {
      gload_lds16(Ap + (size_t)i * 32 * K + k0, As + i * 4096 + tid * 16);
      gload_lds16(Bp + (size_t)i * 32 * K + k0, Bs + i * 4096 + tid * 16);
    }
    __syncthreads();
#pragma unroll
    for (int ks = 0; ks < 2; ks++) {
      int ch = ks * 4 + l4;
      bf16x8 af[4], bfv[4];
#pragma unroll
      for (int mi = 0; mi < 4; mi++)
        af[mi] = *reinterpret_cast<const bf16x8*>(As + swz128(wr * 64 + mi * 16 + l15, ch));
#pragma unroll
      for (int nj = 0; nj < 4; nj++)
        bfv[nj] = *reinterpret_cast<const bf16x8*>(Bs + swz128(wc * 64 + nj * 16 + l15, ch));
#pragma unroll
      for (int nj = 0; nj < 4; nj++)
#pragma unroll
        for (int mi = 0; mi < 4; mi++)
          acc[nj][mi] = __builtin_amdgcn_mfma_f32_16x16x32_bf16(bfv[nj], af[mi], acc[nj][mi], 0, 0, 0);
    }
  }

  // epilogue: lane holds C[m][nb..nb+3], m = ..+l15, nb = ..+l4*4
#pragma unroll
  for (int nj = 0; nj < 4; nj++) {
    int nb = n0 + wc * 64 + nj * 16 + l4 * 4;
    float4 bv = *reinterpret_cast<const float4*>(bias + nb);
#pragma unroll
    for (int mi = 0; mi < 4; mi++) {
      int m = m0 + wr * 64 + mi * 16 + l15;
      f32x4 a = acc[nj][mi];
      float v0 = a[0] + bv.x, v1 = a[1] + bv.y, v2 = a[2] + bv.z, v3 = a[3] + bv.w;
      if (EPI == 1) {
        *reinterpret_cast<float4*>(Cout + (size_t)m * N + nb) = make_float4(v0, v1, v2, v3);
      } else {
        int b = m >> 11, s = m & 2047;
        int sec = nb >> 10, c = nb & 1023, h = c >> 6, d = c & 63;  // sec,h wave-uniform
        size_t bh = (size_t)(b * NH + h);
        if (sec == 0) {
          *reinterpret_cast<uint2*>(Qo + (bh * SEQ + s) * HD + d) =
              make_uint2(pk2(v0 * QSCALE, v1 * QSCALE), pk2(v2 * QSCALE, v3 * QSCALE));
        } else if (sec == 1) {
          *reinterpret_cast<uint2*>(Ko + (bh * SEQ + s) * HD + d) =
              make_uint2(pk2(v0, v1), pk2(v2, v3));
        } else {
          // V transposed: [bh][d][s]; lanes (l15 = s) make 32B contiguous runs
          u16* vt = Vto + (bh * HD + d) * SEQ + s;
          vt[0]       = f2bf(v0);
          vt[SEQ]     = f2bf(v1);
          vt[2 * SEQ] = f2bf(v2);
          vt[3 * SEQ] = f2bf(v3);
        }
      }
    }
  }
}

// ---------------- causal flash attention: 4 waves, kv-parity split ----------------
// r10 structure (best measured): KV staged via gload_lds double-buffer, one
// barrier per step; DEFERRED PV carried in regs across the barrier; exp2-domain
// softmax; ones-MFMA row-sums; defer-max skip.
__global__ __launch_bounds__(256, 2) void attn_kernel(
    const u16* __restrict__ Q, const u16* __restrict__ K,
    const u16* __restrict__ Vt, u16* __restrict__ O) {
  __shared__ __align__(16) char lds[81920];  // K 2x16KB | V 2x16KB | P 4x4KB
  int tid = threadIdx.x, lane = tid & 63, w = tid >> 6;
  int l15 = lane & 15, l4 = lane >> 4;
  int sub = w & 1, par = w >> 1;
  int blk = blockIdx.x;
  int bh = (blk & 7) * 4 + ((blk >> 3) & 3);
  int p = blk >> 5;
  const u16* Qh = Q + (size_t)bh * SEQ * HD;
  const u16* Kh = K + (size_t)bh * SEQ * HD;
  const u16* Vh = Vt + (size_t)bh * HD * SEQ;
  char* Pw = lds + 65536 + w * 4096;
  int srow = tid >> 3, sch = tid & 7;
  int b_ = bh >> 4, h_ = bh & 15;

  bf16x8 onesf;
#pragma unroll
  for (int j = 0; j < 8; j++) onesf[j] = (short)0x3F80;  // bf16 1.0

  auto stageKV = [&](int b, int T) {
    const u16* Kt = Kh + (size_t)T * 128 * HD;
    const u16* Vs = Vh + (size_t)T * 128;
    char* Kb = lds + b * 16384;
    char* Vb = lds + 32768 + b * 16384;
#pragma unroll
    for (int i = 0; i < 4; i++) {
      int row = i * 32 + srow;
      int c = (sch ^ (row & 7)) << 3;
      gload_lds16(Kt + (size_t)row * HD + c, Kb + row * 128 + sch * 16);
    }
#pragma unroll
    for (int sv = 0; sv < 2; sv++)
#pragma unroll
      for (int i = 0; i < 2; i++) {
        int d = i * 32 + srow;
        int c = (sch ^ (d & 7)) << 3;
        gload_lds16(Vs + (size_t)d * SEQ + sv * 64 + c, Vb + sv * 8192 + d * 128 + sch * 16);
      }
  };

  int buf = 0;
  stageKV(0, 0);
  __syncthreads();

  for (int pass = 0; pass < 2; pass++) {
    int qt = (pass == 0) ? (31 - p) : p;
    int nT = (qt + 2) >> 1;
    int qb = qt * 64 + sub * 32;

    bf16x8 qf[2][2];
#pragma unroll
    for (int mi = 0; mi < 2; mi++)
#pragma unroll
      for (int ks = 0; ks < 2; ks++)
        qf[mi][ks] = *reinterpret_cast<const bf16x8*>(
            Qh + (size_t)(qb + mi * 16 + l15) * HD + ks * 32 + l4 * 8);

    float mrun[2] = {-1e30f, -1e30f};
    f32x4 oacc[4][2] = {};
    f32x4 acc_l[2] = {};
    bf16x8 pf_c[2][2], vf_c[4][2];   // deferred-PV carry registers
    bool pend = false;

    for (int T = 0; T < nT; T++) {
      int nxt = (T + 1 < nT) ? (T + 1) : (pass == 0 ? 0 : -1);
      if (nxt >= 0) stageKV(buf ^ 1, nxt);

      char* Kw = lds + buf * 16384 + par * 8192;
      char* Vw = lds + 32768 + buf * 16384 + par * 8192;
      int kvb = T * 128 + par * 64;

      __builtin_amdgcn_s_setprio(1);
      // deferred PV(T-1): pure-reg MFMAs, overlap with QK's ds_reads
      if (pend) {
#pragma unroll
        for (int ks = 0; ks < 2; ks++) {
#pragma unroll
          for (int nd = 0; nd < 4; nd++)
#pragma unroll
            for (int mi = 0; mi < 2; mi++)
              oacc[nd][mi] = __builtin_amdgcn_mfma_f32_16x16x32_bf16(
                  vf_c[nd][ks], pf_c[mi][ks], oacc[nd][mi], 0, 0, 0);
#pragma unroll
          for (int mi = 0; mi < 2; mi++)
            acc_l[mi] = __builtin_amdgcn_mfma_f32_16x16x32_bf16(
                onesf, pf_c[mi][ks], acc_l[mi], 0, 0, 0);
        }
      }

      // S^T = K . Q^T (exp2 domain; D: row = kv = l4*4+r, col = q = l15)
      f32x4 s[4][2] = {};
#pragma unroll
      for (int ks = 0; ks < 2; ks++)
#pragma unroll
        for (int nj = 0; nj < 4; nj++) {
          bf16x8 kf = *reinterpret_cast<const bf16x8*>(Kw + swz128(nj * 16 + l15, ks * 4 + l4));
#pragma unroll
          for (int mi = 0; mi < 2; mi++)
            s[nj][mi] = __builtin_amdgcn_mfma_f32_16x16x32_bf16(kf, qf[mi][ks], s[nj][mi], 0, 0, 0);
        }
      __builtin_amdgcn_s_setprio(0);

      // V fragments for THIS tile (consumed by next step's deferred PV)
#pragma unroll
      for (int ks = 0; ks < 2; ks++)
#pragma unroll
        for (int nd = 0; nd < 4; nd++)
          vf_c[nd][ks] = *reinterpret_cast<const bf16x8*>(Vw + swz128(nd * 16 + l15, ks * 4 + l4));

      if (kvb + 63 > qb) {
#pragma unroll
        for (int nj = 0; nj < 4; nj++)
#pragma unroll
          for (int mi = 0; mi < 2; mi++) {
            int qg = qb + mi * 16 + l15;
#pragma unroll
            for (int r = 0; r < 4; r++) {
              int kg = kvb + nj * 16 + l4 * 4 + r;
              if (kg > qg) s[nj][mi][r] = MVAL;
            }
          }
      }

      // tile row-max (q lane-local, reduce across l4)
      float mt[2];
#pragma unroll
      for (int mi = 0; mi < 2; mi++) {
        float m = s[0][mi][0];
#pragma unroll
        for (int nj = 0; nj < 4; nj++)
#pragma unroll
          for (int r = 0; r < 4; r++) m = fmaxf(m, s[nj][mi][r]);
        m = fmaxf(m, __shfl_xor(m, 16));
        m = fmaxf(m, __shfl_xor(m, 32));
        mt[mi] = m;
      }

      // defer-max: skip rescale when running max unchanged (exact, THR=0)
      if (!__all((mt[0] <= mrun[0]) & (mt[1] <= mrun[1]))) {
#pragma unroll
        for (int mi = 0; mi < 2; mi++) {
          float mnew = fmaxf(mrun[mi], mt[mi]);
          float alpha = EXP2(mrun[mi] - mnew);
          mrun[mi] = mnew;
#pragma unroll
          for (int nd = 0; nd < 4; nd++)
#pragma unroll
            for (int r = 0; r < 4; r++) oacc[nd][mi][r] *= alpha;
#pragma unroll
          for (int r = 0; r < 4; r++) acc_l[mi][r] *= alpha;
        }
      }

      // P = exp2(s - m) -> bf16 P in per-wave LDS
#pragma unroll
      for (int mi = 0; mi < 2; mi++) {
        int prow = mi * 16 + l15;
#pragma unroll
        for (int nj = 0; nj < 4; nj++) {
          float p0 = EXP2(s[nj][mi][0] - mrun[mi]);
          float p1 = EXP2(s[nj][mi][1] - mrun[mi]);
          float p2 = EXP2(s[nj][mi][2] - mrun[mi]);
          float p3 = EXP2(s[nj][mi][3] - mrun[mi]);
          int chunk = nj * 2 + (l4 >> 1);
          char* dst = Pw + prow * 128 + (((chunk ^ (prow & 7)) & 7) << 4) + (l4 & 1) * 8;
          *reinterpret_cast<uint2*>(dst) = make_uint2(pk2(p0, p1), pk2(p2, p3));
        }
      }

      asm volatile("s_waitcnt lgkmcnt(0)" ::: "memory");
      __builtin_amdgcn_sched_barrier(0);

      // P fragments into carry regs (consumed next step)
#pragma unroll
      for (int mi = 0; mi < 2; mi++)
#pragma unroll
        for (int ks = 0; ks < 2; ks++)
          pf_c[mi][ks] = *reinterpret_cast<const bf16x8*>(Pw + swz128(mi * 16 + l15, ks * 4 + l4));
      pend = true;

      __syncthreads();
      buf ^= 1;
    }

    // flush last pending PV
    __builtin_amdgcn_s_setprio(1);
#pragma unroll
    for (int ks = 0; ks < 2; ks++) {
#pragma unroll
      for (int nd = 0; nd < 4; nd++)
#pragma unroll
        for (int mi = 0; mi < 2; mi++)
          oacc[nd][mi] = __builtin_amdgcn_mfma_f32_16x16x32_bf16(
              vf_c[nd][ks], pf_c[mi][ks], oacc[nd][mi], 0, 0, 0);
#pragma unroll
      for (int mi = 0; mi < 2; mi++)
        acc_l[mi] = __builtin_amdgcn_mfma_f32_16x16x32_bf16(
            onesf, pf_c[mi][ks], acc_l[mi], 0, 0, 0);
    }
    __builtin_amdgcn_s_setprio(0);

    // ---- cross-parity merge through the dead K buffer (fp32 exact) ----
    char* Xo = lds + (buf ^ 1) * 16384;
    float* Xml = (float*)(lds + 65536);
    if (par == 1) {
#pragma unroll
      for (int mi = 0; mi < 2; mi++) {
        int row = sub * 32 + mi * 16 + l15;
        if (l4 == 0) {
          Xml[row * 2] = mrun[mi];
          Xml[row * 2 + 1] = acc_l[mi][0];
        }
#pragma unroll
        for (int nd = 0; nd < 4; nd++)
          *reinterpret_cast<f32x4*>(Xo + row * 256 + (((nd * 4 + l4) ^ (row & 7)) << 4)) =
              oacc[nd][mi];
      }
    }
    __syncthreads();
    if (par == 0) {
#pragma unroll
      for (int mi = 0; mi < 2; mi++) {
        int row = sub * 32 + mi * 16 + l15;
        float mB = Xml[row * 2], lB = Xml[row * 2 + 1];
        float m = fmaxf(mrun[mi], mB);
        float wA = EXP2(mrun[mi] - m), wB = EXP2(mB - m);
        float linv = 1.0f / (acc_l[mi][0] * wA + lB * wB);
        float fA = wA * linv, fB = wB * linv;
        u16* orow = O + ((size_t)b_ * SEQ + qt * 64 + sub * 32 + mi * 16 + l15) * DIM + h_ * HD;
#pragma unroll
        for (int nd = 0; nd < 4; nd++) {
          f32x4 ob = *reinterpret_cast<const f32x4*>(
              Xo + row * 256 + (((nd * 4 + l4) ^ (row & 7)) << 4));
          float o0 = oacc[nd][mi][0] * fA + ob[0] * fB;
          float o1 = oacc[nd][mi][1] * fA + ob[1] * fB;
          float o2 = oacc[nd][mi][2] * fA + ob[2] * fB;
          float o3 = oacc[nd][mi][3] * fA + ob[3] * fB;
          *reinterpret_cast<uint2*>(orow + nd * 16 + l4 * 4) = make_uint2(pk2(o0, o1), pk2(o2, o3));
        }
      }
    }
    __syncthreads();
  }
}

extern "C" void kernel_launch(void* const* d_in, const int* in_sizes, int n_in,
                              void* d_out, int out_size, void* d_ws, size_t ws_size,
                              hipStream_t stream) {
  const float* x     = (const float*)d_in[0];
  const float* W_qkv = (const float*)d_in[1];
  const float* b_qkv = (const float*)d_in[2];
  const float* W_out = (const float*)d_in[3];
  const float* b_out = (const float*)d_in[4];
  float* out = (float*)d_out;
  char* ws = (char*)d_ws;

  // ws layout (bytes)
  u16* xb    = (u16*)(ws);                               // 8 MB  [4096][1024]
  u16* WqkvT = (u16*)(ws + 8388608);                     // 6 MB  [3072][1024]
  u16* WoutT = (u16*)(ws + 8388608 + 6291456);           // 2 MB  [1024][1024]
  u16* Qb    = (u16*)(ws + 16777216);                    // 8 MB  [32][2048][64]
  u16* Kb    = (u16*)(ws + 16777216 + 8388608);          // 8 MB  [32][2048][64]
  u16* Vtb   = (u16*)(ws + 16777216 + 2 * 8388608);      // 8 MB  [32][64][2048]
  u16* Ob    = (u16*)(ws + 16777216 + 3 * 8388608);      // 8 MB  [4096][1024]

  prep_kernel<<<4096 + 3072 + 1024, 256, 0, stream>>>(x, xb, W_qkv, WqkvT, W_out, WoutT);
  gemm_bt_kernel<0><<<dim3(3 * DIM / 128, BATCH * SEQ / 128), 256, 0, stream>>>(
      xb, WqkvT, b_qkv, nullptr, Qb, Kb, Vtb, BATCH * SEQ, 3 * DIM, DIM);
  attn_kernel<<<512, 256, 0, stream>>>(Qb, Kb, Vtb, Ob);
  gemm_bt_kernel<1><<<dim3(DIM / 128, BATCH * SEQ / 128), 256, 0, stream>>>(
      Ob, WoutT, b_out, out, nullptr, nullptr, nullptr, BATCH * SEQ, DIM, DIM);
}

// Round 14
// 110.981 us; speedup vs baseline: 1.1798x; 1.0089x over previous
//
#include <hip/hip_runtime.h>
#include <hip/hip_bf16.h>
#include <stdint.h>

#define BATCH 2
#define SEQ   2048
#define DIM   1024
#define NH    16
#define HD    64
#define MVAL  (-10000.0f)

// Native exp2 (raw v_exp_f32, no libm fixup). Fallback: e-domain with __expf.
#if __has_builtin(__builtin_amdgcn_exp2f)
#define EXP2(x) __builtin_amdgcn_exp2f(x)
#define QSCALE  (0.125f * 1.44269504f)   // fold softmax scale AND log2(e) into Q
#else
#define EXP2(x) __expf(x)
#define QSCALE  0.125f
#endif

typedef __attribute__((ext_vector_type(8))) short bf16x8;
typedef __attribute__((ext_vector_type(4))) float f32x4;
typedef unsigned short u16;

static __device__ __forceinline__ u16 f2bf(float f) {
  union { float f; uint32_t u; } c; c.f = f;
  uint32_t x = c.u;
  return (u16)((x + 0x7fffu + ((x >> 16) & 1u)) >> 16);  // RNE
}

static __device__ __forceinline__ uint32_t pk2(float a, float b) {
  __hip_bfloat162 h = __float22bfloat162_rn(make_float2(a, b));
  union { __hip_bfloat162 h; uint32_t u; } c; c.h = h;
  return c.u;
}

// swizzled byte offset within LDS tiles of 128B rows (8 x 16B chunks)
static __device__ __forceinline__ int swz128(int row, int chunk) {
  return row * 128 + (((chunk ^ (row & 7)) & 7) << 4);
}

static __device__ __forceinline__ void gload_lds16(const void* g, void* l) {
  __builtin_amdgcn_global_load_lds((const __attribute__((address_space(1))) void*)g,
                                   (__attribute__((address_space(3))) void*)l, 16, 0, 0);
}

// -------- fused prep: fp32->bf16 convert of x + both weight transposes --------
__global__ void prep_kernel(const float* __restrict__ x, u16* __restrict__ xb,
                            const float* __restrict__ Wqkv, u16* __restrict__ WqkvT,
                            const float* __restrict__ Wout, u16* __restrict__ WoutT) {
  __shared__ float tile[32][33];
  int blk = blockIdx.x, tid = threadIdx.x;
  if (blk < 4096) {
    int i = blk * 256 + tid;
    float4 v = reinterpret_cast<const float4*>(x)[i];
    reinterpret_cast<uint2*>(xb)[i] = make_uint2(pk2(v.x, v.y), pk2(v.z, v.w));
    return;
  }
  const float* in;
  u16* out;
  int C, t;
  if (blk < 4096 + 3072) { t = blk - 4096; in = Wqkv; out = WqkvT; C = 3072; }
  else                   { t = blk - 7168; in = Wout; out = WoutT; C = 1024; }
  int R = DIM;
  int c0 = (t % (C / 32)) * 32, r0 = (t / (C / 32)) * 32;
  int tx = tid & 31, ty = tid >> 5;
#pragma unroll
  for (int i = 0; i < 32; i += 8)
    tile[ty + i][tx] = in[(size_t)(r0 + ty + i) * C + c0 + tx];
  __syncthreads();
#pragma unroll
  for (int i = 0; i < 32; i += 8)
    out[(size_t)(c0 + ty + i) * R + r0 + tx] = f2bf(tile[tx][ty + i]);
}

// ---------------- bf16 GEMM: C = A[M,K] * Bt[N,K]^T + bias ----------------
// Swizzled LDS (pre-swizzled gload_lds source + swizzled ds_read_b128).
// SWAPPED mfma operands: lane's acc quad holds 4 consecutive n -> packed stores.
// EPI==0: Q (x QSCALE) / K head-split [bh][s][d] bf16 (8B stores);
//         V written TRANSPOSED [bh][d][s] directly (2B stores, 32B lane-runs).
// EPI==1: plain fp32 [M][N], 16B stores
template <int EPI>
__global__ __launch_bounds__(256, 2) void gemm_bt_kernel(
    const u16* __restrict__ A, const u16* __restrict__ Bt,
    const float* __restrict__ bias, float* __restrict__ Cout,
    u16* __restrict__ Qo, u16* __restrict__ Ko, u16* __restrict__ Vto,
    int M, int N, int K) {
  __shared__ __align__(16) char lds[32768];
  char* As = lds;            // 128 rows x 64 bf16, swizzled
  char* Bs = lds + 16384;
  int tid = threadIdx.x;
  int lane = tid & 63, l15 = lane & 15, l4 = lane >> 4;
  int w = tid >> 6, wr = w >> 1, wc = w & 1;
  int m0 = blockIdx.y * 128, n0 = blockIdx.x * 128;
  int srow = tid >> 3, sch = tid & 7;
  int sc_swz = ((sch ^ (srow & 7)) << 3);  // pre-swizzled source chunk (u16 units)

  const u16* Ap = A + (size_t)(m0 + srow) * K + sc_swz;
  const u16* Bp = Bt + (size_t)(n0 + srow) * K + sc_swz;

  f32x4 acc[4][4] = {};  // acc[nj][mi]: quad holds 4 consecutive n

  for (int k0 = 0; k0 < K; k0 += 64) {
    __syncthreads();
#pragma unroll
    for (int i = 0; i < 4; i++) {
      gload_lds16(Ap + (size_t)i * 32 * K + k0, As + i * 4096 + tid * 16);
      gload_lds16(Bp + (size_t)i * 32 * K + k0, Bs + i * 4096 + tid * 16);
    }
    __syncthreads();
#pragma unroll
    for (int ks = 0; ks < 2; ks++) {
      int ch = ks * 4 + l4;
      bf16x8 af[4], bfv[4];
#pragma unroll
      for (int mi = 0; mi < 4; mi++)
        af[mi] = *reinterpret_cast<const bf16x8*>(As + swz128(wr * 64 + mi * 16 + l15, ch));
#pragma unroll
      for (int nj = 0; nj < 4; nj++)
        bfv[nj] = *reinterpret_cast<const bf16x8*>(Bs + swz128(wc * 64 + nj * 16 + l15, ch));
#pragma unroll
      for (int nj = 0; nj < 4; nj++)
#pragma unroll
        for (int mi = 0; mi < 4; mi++)
          acc[nj][mi] = __builtin_amdgcn_mfma_f32_16x16x32_bf16(bfv[nj], af[mi], acc[nj][mi], 0, 0, 0);
    }
  }

  // epilogue: lane holds C[m][nb..nb+3], m = ..+l15, nb = ..+l4*4
#pragma unroll
  for (int nj = 0; nj < 4; nj++) {
    int nb = n0 + wc * 64 + nj * 16 + l4 * 4;
    float4 bv = *reinterpret_cast<const float4*>(bias + nb);
#pragma unroll
    for (int mi = 0; mi < 4; mi++) {
      int m = m0 + wr * 64 + mi * 16 + l15;
      f32x4 a = acc[nj][mi];
      float v0 = a[0] + bv.x, v1 = a[1] + bv.y, v2 = a[2] + bv.z, v3 = a[3] + bv.w;
      if (EPI == 1) {
        *reinterpret_cast<float4*>(Cout + (size_t)m * N + nb) = make_float4(v0, v1, v2, v3);
      } else {
        int b = m >> 11, s = m & 2047;
        int sec = nb >> 10, c = nb & 1023, h = c >> 6, d = c & 63;  // sec,h wave-uniform
        size_t bh = (size_t)(b * NH + h);
        if (sec == 0) {
          *reinterpret_cast<uint2*>(Qo + (bh * SEQ + s) * HD + d) =
              make_uint2(pk2(v0 * QSCALE, v1 * QSCALE), pk2(v2 * QSCALE, v3 * QSCALE));
        } else if (sec == 1) {
          *reinterpret_cast<uint2*>(Ko + (bh * SEQ + s) * HD + d) =
              make_uint2(pk2(v0, v1), pk2(v2, v3));
        } else {
          // V transposed: [bh][d][s]; lanes (l15 = s) make 32B contiguous runs
          u16* vt = Vto + (bh * HD + d) * SEQ + s;
          vt[0]       = f2bf(v0);
          vt[SEQ]     = f2bf(v1);
          vt[2 * SEQ] = f2bf(v2);
          vt[3 * SEQ] = f2bf(v3);
        }
      }
    }
  }
}

// ------- causal flash attention: DUAL-CHUNK single kv sweep -------
// 512 blocks x 256 thr. Block = (bh, p): chunks A = 31-p and B = p processed
// SIMULTANEOUSLY over one staged kv stream (B's range subset of A's). K/V
// fragments read from LDS once per tile, reused for both chunks -> LDS
// bytes/MFMA halve vs two passes. 4 waves: sub = q 32-half, par = kv 64-half.
// Merges for A (dead K buf) and B (dead V buf) share one barrier pair.
__global__ __launch_bounds__(256, 2) void attn_kernel(
    const u16* __restrict__ Q, const u16* __restrict__ K,
    const u16* __restrict__ Vt, u16* __restrict__ O) {
  __shared__ __align__(16) char lds[81920];  // K 2x16KB | V 2x16KB | P 4x4KB
  int tid = threadIdx.x, lane = tid & 63, w = tid >> 6;
  int l15 = lane & 15, l4 = lane >> 4;
  int sub = w & 1, par = w >> 1;
  int blk = blockIdx.x;
  int bh = (blk & 7) * 4 + ((blk >> 3) & 3);
  int p = blk >> 5;                         // [0,16)
  int qtA = 31 - p, qtB = p;
  int nTA = (qtA + 2) >> 1, nTB = (qtB + 2) >> 1;
  int qbA = qtA * 64 + sub * 32, qbB = qtB * 64 + sub * 32;
  const u16* Qh = Q + (size_t)bh * SEQ * HD;
  const u16* Kh = K + (size_t)bh * SEQ * HD;
  const u16* Vh = Vt + (size_t)bh * HD * SEQ;
  char* Pw = lds + 65536 + w * 4096;
  int srow = tid >> 3, sch = tid & 7;
  int b_ = bh >> 4, h_ = bh & 15;

  bf16x8 onesf;
#pragma unroll
  for (int j = 0; j < 8; j++) onesf[j] = (short)0x3F80;  // bf16 1.0

  auto stageKV = [&](int b, int T) {
    const u16* Kt = Kh + (size_t)T * 128 * HD;
    const u16* Vs = Vh + (size_t)T * 128;
    char* Kb = lds + b * 16384;
    char* Vb = lds + 32768 + b * 16384;
#pragma unroll
    for (int i = 0; i < 4; i++) {
      int row = i * 32 + srow;
      int c = (sch ^ (row & 7)) << 3;
      gload_lds16(Kt + (size_t)row * HD + c, Kb + row * 128 + sch * 16);
    }
#pragma unroll
    for (int sv = 0; sv < 2; sv++)
#pragma unroll
      for (int i = 0; i < 2; i++) {
        int d = i * 32 + srow;
        int c = (sch ^ (d & 7)) << 3;
        gload_lds16(Vs + (size_t)d * SEQ + sv * 64 + c, Vb + sv * 8192 + d * 128 + sch * 16);
      }
  };

  // Q fragments for both chunks (pre-scaled by QSCALE in gemm epilogue)
  bf16x8 qfA[2][2], qfB[2][2];
#pragma unroll
  for (int mi = 0; mi < 2; mi++)
#pragma unroll
    for (int ks = 0; ks < 2; ks++) {
      qfA[mi][ks] = *reinterpret_cast<const bf16x8*>(
          Qh + (size_t)(qbA + mi * 16 + l15) * HD + ks * 32 + l4 * 8);
      qfB[mi][ks] = *reinterpret_cast<const bf16x8*>(
          Qh + (size_t)(qbB + mi * 16 + l15) * HD + ks * 32 + l4 * 8);
    }

  float mrunA[2] = {-1e30f, -1e30f}, mrunB[2] = {-1e30f, -1e30f};
  f32x4 oaccA[4][2] = {}, oaccB[4][2] = {};
  f32x4 acclA[2] = {}, acclB[2] = {};

  int buf = 0;
  stageKV(0, 0);
  __syncthreads();

  for (int T = 0; T < nTA; T++) {
    if (T + 1 < nTA) stageKV(buf ^ 1, T + 1);
    char* Kw = lds + buf * 16384 + par * 8192;
    char* Vw = lds + 32768 + buf * 16384 + par * 8192;
    int kvb = T * 128 + par * 64;
    bool doB = (T < nTB);

    // K fragments ONCE, reused for both chunks' QK
    bf16x8 kf[2][4];
#pragma unroll
    for (int ks = 0; ks < 2; ks++)
#pragma unroll
      for (int nj = 0; nj < 4; nj++)
        kf[ks][nj] = *reinterpret_cast<const bf16x8*>(Kw + swz128(nj * 16 + l15, ks * 4 + l4));

    // ---- chunk A: QK ----
    f32x4 s[4][2] = {};
    __builtin_amdgcn_s_setprio(1);
#pragma unroll
    for (int ks = 0; ks < 2; ks++)
#pragma unroll
      for (int nj = 0; nj < 4; nj++)
#pragma unroll
        for (int mi = 0; mi < 2; mi++)
          s[nj][mi] = __builtin_amdgcn_mfma_f32_16x16x32_bf16(kf[ks][nj], qfA[mi][ks], s[nj][mi], 0, 0, 0);
    __builtin_amdgcn_s_setprio(0);

    // ---- softmax A -> P_A ----
    if (kvb + 63 > qbA) {
#pragma unroll
      for (int nj = 0; nj < 4; nj++)
#pragma unroll
        for (int mi = 0; mi < 2; mi++) {
          int qg = qbA + mi * 16 + l15;
#pragma unroll
          for (int r = 0; r < 4; r++) {
            int kg = kvb + nj * 16 + l4 * 4 + r;
            if (kg > qg) s[nj][mi][r] = MVAL;
          }
        }
    }
    {
      float mt[2];
#pragma unroll
      for (int mi = 0; mi < 2; mi++) {
        float m = s[0][mi][0];
#pragma unroll
        for (int nj = 0; nj < 4; nj++)
#pragma unroll
          for (int r = 0; r < 4; r++) m = fmaxf(m, s[nj][mi][r]);
        m = fmaxf(m, __shfl_xor(m, 16));
        m = fmaxf(m, __shfl_xor(m, 32));
        mt[mi] = m;
      }
      if (!__all((mt[0] <= mrunA[0]) & (mt[1] <= mrunA[1]))) {
#pragma unroll
        for (int mi = 0; mi < 2; mi++) {
          float mnew = fmaxf(mrunA[mi], mt[mi]);
          float alpha = EXP2(mrunA[mi] - mnew);
          mrunA[mi] = mnew;
#pragma unroll
          for (int nd = 0; nd < 4; nd++)
#pragma unroll
            for (int r = 0; r < 4; r++) oaccA[nd][mi][r] *= alpha;
#pragma unroll
          for (int r = 0; r < 4; r++) acclA[mi][r] *= alpha;
        }
      }
#pragma unroll
      for (int mi = 0; mi < 2; mi++) {
        int prow = mi * 16 + l15;
#pragma unroll
        for (int nj = 0; nj < 4; nj++) {
          float p0 = EXP2(s[nj][mi][0] - mrunA[mi]);
          float p1 = EXP2(s[nj][mi][1] - mrunA[mi]);
          float p2 = EXP2(s[nj][mi][2] - mrunA[mi]);
          float p3 = EXP2(s[nj][mi][3] - mrunA[mi]);
          int chunk = nj * 2 + (l4 >> 1);
          char* dst = Pw + prow * 128 + (((chunk ^ (prow & 7)) & 7) << 4) + (l4 & 1) * 8;
          *reinterpret_cast<uint2*>(dst) = make_uint2(pk2(p0, p1), pk2(p2, p3));
        }
      }
    }

    // ---- chunk B: QK (overlaps P_A write drain) ----
    f32x4 sB[4][2] = {};
    if (doB) {
      __builtin_amdgcn_s_setprio(1);
#pragma unroll
      for (int ks = 0; ks < 2; ks++)
#pragma unroll
        for (int nj = 0; nj < 4; nj++)
#pragma unroll
          for (int mi = 0; mi < 2; mi++)
            sB[nj][mi] = __builtin_amdgcn_mfma_f32_16x16x32_bf16(kf[ks][nj], qfB[mi][ks], sB[nj][mi], 0, 0, 0);
      __builtin_amdgcn_s_setprio(0);
    }

    asm volatile("s_waitcnt lgkmcnt(0)" ::: "memory");
    __builtin_amdgcn_sched_barrier(0);
    bf16x8 pfA[2][2];
#pragma unroll
    for (int mi = 0; mi < 2; mi++)
#pragma unroll
      for (int ks = 0; ks < 2; ks++)
        pfA[mi][ks] = *reinterpret_cast<const bf16x8*>(Pw + swz128(mi * 16 + l15, ks * 4 + l4));

    // ---- softmax B -> P_B (overwrites Pw; pfA already in regs) ----
    if (doB) {
      if (kvb + 63 > qbB) {
#pragma unroll
        for (int nj = 0; nj < 4; nj++)
#pragma unroll
          for (int mi = 0; mi < 2; mi++) {
            int qg = qbB + mi * 16 + l15;
#pragma unroll
            for (int r = 0; r < 4; r++) {
              int kg = kvb + nj * 16 + l4 * 4 + r;
              if (kg > qg) sB[nj][mi][r] = MVAL;
            }
          }
      }
      float mt[2];
#pragma unroll
      for (int mi = 0; mi < 2; mi++) {
        float m = sB[0][mi][0];
#pragma unroll
        for (int nj = 0; nj < 4; nj++)
#pragma unroll
          for (int r = 0; r < 4; r++) m = fmaxf(m, sB[nj][mi][r]);
        m = fmaxf(m, __shfl_xor(m, 16));
        m = fmaxf(m, __shfl_xor(m, 32));
        mt[mi] = m;
      }
      if (!__all((mt[0] <= mrunB[0]) & (mt[1] <= mrunB[1]))) {
#pragma unroll
        for (int mi = 0; mi < 2; mi++) {
          float mnew = fmaxf(mrunB[mi], mt[mi]);
          float alpha = EXP2(mrunB[mi] - mnew);
          mrunB[mi] = mnew;
#pragma unroll
          for (int nd = 0; nd < 4; nd++)
#pragma unroll
            for (int r = 0; r < 4; r++) oaccB[nd][mi][r] *= alpha;
#pragma unroll
          for (int r = 0; r < 4; r++) acclB[mi][r] *= alpha;
        }
      }
#pragma unroll
      for (int mi = 0; mi < 2; mi++) {
        int prow = mi * 16 + l15;
#pragma unroll
        for (int nj = 0; nj < 4; nj++) {
          float p0 = EXP2(sB[nj][mi][0] - mrunB[mi]);
          float p1 = EXP2(sB[nj][mi][1] - mrunB[mi]);
          float p2 = EXP2(sB[nj][mi][2] - mrunB[mi]);
          float p3 = EXP2(sB[nj][mi][3] - mrunB[mi]);
          int chunk = nj * 2 + (l4 >> 1);
          char* dst = Pw + prow * 128 + (((chunk ^ (prow & 7)) & 7) << 4) + (l4 & 1) * 8;
          *reinterpret_cast<uint2*>(dst) = make_uint2(pk2(p0, p1), pk2(p2, p3));
        }
      }
    }

    // V fragments ONCE, reused for both chunks' PV
    bf16x8 vf[4][2];
#pragma unroll
    for (int ks = 0; ks < 2; ks++)
#pragma unroll
      for (int nd = 0; nd < 4; nd++)
        vf[nd][ks] = *reinterpret_cast<const bf16x8*>(Vw + swz128(nd * 16 + l15, ks * 4 + l4));

    // ---- PV_A (covers P_B write drain) ----
    __builtin_amdgcn_s_setprio(1);
#pragma unroll
    for (int ks = 0; ks < 2; ks++) {
#pragma unroll
      for (int nd = 0; nd < 4; nd++)
#pragma unroll
        for (int mi = 0; mi < 2; mi++)
          oaccA[nd][mi] = __builtin_amdgcn_mfma_f32_16x16x32_bf16(
              vf[nd][ks], pfA[mi][ks], oaccA[nd][mi], 0, 0, 0);
#pragma unroll
      for (int mi = 0; mi < 2; mi++)
        acclA[mi] = __builtin_amdgcn_mfma_f32_16x16x32_bf16(onesf, pfA[mi][ks], acclA[mi], 0, 0, 0);
    }
    __builtin_amdgcn_s_setprio(0);

    // ---- PV_B ----
    if (doB) {
      asm volatile("s_waitcnt lgkmcnt(0)" ::: "memory");
      __builtin_amdgcn_sched_barrier(0);
      bf16x8 pfB[2][2];
#pragma unroll
      for (int mi = 0; mi < 2; mi++)
#pragma unroll
        for (int ks = 0; ks < 2; ks++)
          pfB[mi][ks] = *reinterpret_cast<const bf16x8*>(Pw + swz128(mi * 16 + l15, ks * 4 + l4));
      __builtin_amdgcn_s_setprio(1);
#pragma unroll
      for (int ks = 0; ks < 2; ks++) {
#pragma unroll
        for (int nd = 0; nd < 4; nd++)
#pragma unroll
          for (int mi = 0; mi < 2; mi++)
            oaccB[nd][mi] = __builtin_amdgcn_mfma_f32_16x16x32_bf16(
                vf[nd][ks], pfB[mi][ks], oaccB[nd][mi], 0, 0, 0);
#pragma unroll
        for (int mi = 0; mi < 2; mi++)
          acclB[mi] = __builtin_amdgcn_mfma_f32_16x16x32_bf16(onesf, pfB[mi][ks], acclB[mi], 0, 0, 0);
      }
      __builtin_amdgcn_s_setprio(0);
    }

    __syncthreads();
    buf ^= 1;
  }

  // ---- merges: A through dead K buffer, B through dead V buffer ----
  // after final `buf ^= 1`, `buf` indexes the dead (unread-this-step) buffers
  char* XoA = lds + buf * 16384;
  char* XoB = lds + 32768 + buf * 16384;
  float* XmlA = (float*)(lds + 65536);          // dead P region (wave 0 slice)
  float* XmlB = (float*)(lds + 65536 + 8192);   // dead P region (wave 2 slice)
  if (par == 1) {
#pragma unroll
    for (int mi = 0; mi < 2; mi++) {
      int row = sub * 32 + mi * 16 + l15;
      if (l4 == 0) {
        XmlA[row * 2] = mrunA[mi];
        XmlA[row * 2 + 1] = acclA[mi][0];
        XmlB[row * 2] = mrunB[mi];
        XmlB[row * 2 + 1] = acclB[mi][0];
      }
#pragma unroll
      for (int nd = 0; nd < 4; nd++) {
        *reinterpret_cast<f32x4*>(XoA + row * 256 + (((nd * 4 + l4) ^ (row & 7)) << 4)) =
            oaccA[nd][mi];
        *reinterpret_cast<f32x4*>(XoB + row * 256 + (((nd * 4 + l4) ^ (row & 7)) << 4)) =
            oaccB[nd][mi];
      }
    }
  }
  __syncthreads();
  if (par == 0) {
#pragma unroll
    for (int mi = 0; mi < 2; mi++) {
      int row = sub * 32 + mi * 16 + l15;
      // chunk A
      {
        float mB = XmlA[row * 2], lB = XmlA[row * 2 + 1];
        float m = fmaxf(mrunA[mi], mB);
        float wA = EXP2(mrunA[mi] - m), wB = EXP2(mB - m);
        float linv = 1.0f / (acclA[mi][0] * wA + lB * wB);
        float fA = wA * linv, fB = wB * linv;
        u16* orow = O + ((size_t)b_ * SEQ + qbA + mi * 16 + l15) * DIM + h_ * HD;
#pragma unroll
        for (int nd = 0; nd < 4; nd++) {
          f32x4 ob = *reinterpret_cast<const f32x4*>(
              XoA + row * 256 + (((nd * 4 + l4) ^ (row & 7)) << 4));
          float o0 = oaccA[nd][mi][0] * fA + ob[0] * fB;
          float o1 = oaccA[nd][mi][1] * fA + ob[1] * fB;
          float o2 = oaccA[nd][mi][2] * fA + ob[2] * fB;
          float o3 = oaccA[nd][mi][3] * fA + ob[3] * fB;
          *reinterpret_cast<uint2*>(orow + nd * 16 + l4 * 4) = make_uint2(pk2(o0, o1), pk2(o2, o3));
        }
      }
      // chunk B
      {
        float mB = XmlB[row * 2], lB = XmlB[row * 2 + 1];
        float m = fmaxf(mrunB[mi], mB);
        float wA = EXP2(mrunB[mi] - m), wB = EXP2(mB - m);
        float linv = 1.0f / (acclB[mi][0] * wA + lB * wB);
        float fA = wA * linv, fB = wB * linv;
        u16* orow = O + ((size_t)b_ * SEQ + qbB + mi * 16 + l15) * DIM + h_ * HD;
#pragma unroll
        for (int nd = 0; nd < 4; nd++) {
          f32x4 ob = *reinterpret_cast<const f32x4*>(
              XoB + row * 256 + (((nd * 4 + l4) ^ (row & 7)) << 4));
          float o0 = oaccB[nd][mi][0] * fA + ob[0] * fB;
          float o1 = oaccB[nd][mi][1] * fA + ob[1] * fB;
          float o2 = oaccB[nd][mi][2] * fA + ob[2] * fB;
          float o3 = oaccB[nd][mi][3] * fA + ob[3] * fB;
          *reinterpret_cast<uint2*>(orow + nd * 16 + l4 * 4) = make_uint2(pk2(o0, o1), pk2(o2, o3));
        }
      }
    }
  }
}

extern "C" void kernel_launch(void* const* d_in, const int* in_sizes, int n_in,
                              void* d_out, int out_size, void* d_ws, size_t ws_size,
                              hipStream_t stream) {
  const float* x     = (const float*)d_in[0];
  const float* W_qkv = (const float*)d_in[1];
  const float* b_qkv = (const float*)d_in[2];
  const float* W_out = (const float*)d_in[3];
  const float* b_out = (const float*)d_in[4];
  float* out = (float*)d_out;
  char* ws = (char*)d_ws;

  // ws layout (bytes)
  u16* xb    = (u16*)(ws);                               // 8 MB  [4096][1024]
  u16* WqkvT = (u16*)(ws + 8388608);                     // 6 MB  [3072][1024]
  u16* WoutT = (u16*)(ws + 8388608 + 6291456);           // 2 MB  [1024][1024]
  u16* Qb    = (u16*)(ws + 16777216);                    // 8 MB  [32][2048][64]
  u16* Kb    = (u16*)(ws + 16777216 + 8388608);          // 8 MB  [32][2048][64]
  u16* Vtb   = (u16*)(ws + 16777216 + 2 * 8388608);      // 8 MB  [32][64][2048]
  u16* Ob    = (u16*)(ws + 16777216 + 3 * 8388608);      // 8 MB  [4096][1024]

  prep_kernel<<<4096 + 3072 + 1024, 256, 0, stream>>>(x, xb, W_qkv, WqkvT, W_out, WoutT);
  gemm_bt_kernel<0><<<dim3(3 * DIM / 128, BATCH * SEQ / 128), 256, 0, stream>>>(
      xb, WqkvT, b_qkv, nullptr, Qb, Kb, Vtb, BATCH * SEQ, 3 * DIM, DIM);
  attn_kernel<<<512, 256, 0, stream>>>(Qb, Kb, Vtb, Ob);
  gemm_bt_kernel<1><<<dim3(DIM / 128, BATCH * SEQ / 128), 256, 0, stream>>>(
      Ob, WoutT, b_out, out, nullptr, nullptr, nullptr, BATCH * SEQ, DIM, DIM);
}